// Round 1
// baseline (1908.465 us; speedup 1.0000x reference)
//
#include <hip/hip_runtime.h>
#include <math.h>

#define N     50000
#define F_IN  128
#define HID   256
#define E     800000
#define OUTD  64
#define NEG   0.2f

typedef float4 f4;

static __device__ __forceinline__ float lrelu(float x) { return x >= 0.f ? x : NEG * x; }

// ---------------------------------------------------------------------------
// Projection: h[n,256] = x[n,128] @ W[128,256] + b.  Block = 16 rows x 256 cols,
// 4x4 register tile per thread, transposed LDS x-tile read as broadcast b128.
// ---------------------------------------------------------------------------
__global__ __launch_bounds__(256) void proj_kernel(
    const float* __restrict__ x, const float* __restrict__ W,
    const float* __restrict__ b, float* __restrict__ h)
{
  __shared__ float xT[F_IN * 16];   // [k][i]
  const int t = threadIdx.x;
  const int base = blockIdx.x * 16;
  for (int idx = t; idx < 16 * F_IN; idx += 256) {
    int r = idx >> 7, c = idx & (F_IN - 1);
    xT[c * 16 + r] = x[(size_t)(base + r) * F_IN + c];
  }
  __syncthreads();
  const int ig = t >> 6;
  const int j0 = (t & 63) * 4;
  float acc[4][4] = {};
  for (int k = 0; k < F_IN; ++k) {
    f4 w  = *(const f4*)&W[k * HID + j0];
    f4 xv = *(const f4*)&xT[k * 16 + ig * 4];
    const float wa[4] = {w.x, w.y, w.z, w.w};
    const float xa[4] = {xv.x, xv.y, xv.z, xv.w};
#pragma unroll
    for (int i = 0; i < 4; ++i)
#pragma unroll
      for (int j = 0; j < 4; ++j) acc[i][j] = fmaf(xa[i], wa[j], acc[i][j]);
  }
  f4 bv = *(const f4*)&b[j0];
  const float ba[4] = {bv.x, bv.y, bv.z, bv.w};
#pragma unroll
  for (int i = 0; i < 4; ++i) {
    f4 o = {acc[i][0] + ba[0], acc[i][1] + ba[1], acc[i][2] + ba[2], acc[i][3] + ba[3]};
    *(f4*)&h[(size_t)(base + ig * 4 + i) * HID + j0] = o;
  }
}

// ---------------------------------------------------------------------------
// Per-node attention scores: s_k[n,h] = sum_d h[n,h*32+d]*a_k[h*32+d] for 4
// different a-vectors in one pass over h.  One wave per node.
// ---------------------------------------------------------------------------
__global__ __launch_bounds__(256) void nodescore4_kernel(
    const float* __restrict__ h,
    const float* __restrict__ a0, const float* __restrict__ a1,
    const float* __restrict__ a2, const float* __restrict__ a3,
    float* __restrict__ s0, float* __restrict__ s1,
    float* __restrict__ s2, float* __restrict__ s3)
{
  const int node = (blockIdx.x * 256 + threadIdx.x) >> 6;
  const int lane = threadIdx.x & 63;
  f4 xv = *(const f4*)&h[(size_t)node * HID + lane * 4];
  f4 v0 = *(const f4*)&a0[lane * 4];
  f4 v1 = *(const f4*)&a1[lane * 4];
  f4 v2 = *(const f4*)&a2[lane * 4];
  f4 v3 = *(const f4*)&a3[lane * 4];
  float p0 = xv.x*v0.x + xv.y*v0.y + xv.z*v0.z + xv.w*v0.w;
  float p1 = xv.x*v1.x + xv.y*v1.y + xv.z*v1.z + xv.w*v1.w;
  float p2 = xv.x*v2.x + xv.y*v2.y + xv.z*v2.z + xv.w*v2.w;
  float p3 = xv.x*v3.x + xv.y*v3.y + xv.z*v3.z + xv.w*v3.w;
#pragma unroll
  for (int off = 1; off < 8; off <<= 1) {
    p0 += __shfl_xor(p0, off);
    p1 += __shfl_xor(p1, off);
    p2 += __shfl_xor(p2, off);
    p3 += __shfl_xor(p3, off);
  }
  if ((lane & 7) == 0) {
    int hh = lane >> 3;
    s0[node * 8 + hh] = p0;
    s1[node * 8 + hh] = p1;
    s2[node * 8 + hh] = p2;
    s3[node * 8 + hh] = p3;
  }
}

// ---------------------------------------------------------------------------
// CSR build: histogram, exclusive scan (single block), scatter fill.
// ---------------------------------------------------------------------------
__global__ void hist_kernel(const int* __restrict__ dst, int* __restrict__ count)
{
  int i = blockIdx.x * 256 + threadIdx.x;
  if (i < E) atomicAdd(&count[dst[i]], 1);
}

__global__ __launch_bounds__(1024) void scan_kernel(
    const int* __restrict__ count, int* __restrict__ start, int* __restrict__ cursor)
{
  __shared__ int part[1024];
  const int t = threadIdx.x;
  const int chunk = (N + 1023) / 1024;
  const int b = t * chunk;
  const int e = min(N, b + chunk);
  int s = 0;
  for (int i = b; i < e; ++i) s += count[i];
  part[t] = s;
  __syncthreads();
  for (int off = 1; off < 1024; off <<= 1) {
    int v = (t >= off) ? part[t - off] : 0;
    __syncthreads();
    part[t] += v;
    __syncthreads();
  }
  int run = (t == 0) ? 0 : part[t - 1];
  for (int i = b; i < e; ++i) {
    start[i] = run;
    cursor[i] = run;
    run += count[i];
  }
}

__global__ void fill_kernel(const int* __restrict__ src, const int* __restrict__ dst,
                            int* __restrict__ cursor, int* __restrict__ csr_src)
{
  int i = blockIdx.x * 256 + threadIdx.x;
  if (i < E) {
    int pos = atomicAdd(&cursor[dst[i]], 1);
    csr_src[pos] = src[i];
  }
}

// ---------------------------------------------------------------------------
// Relation conv: one wave per dst node.  Pass 1: per-head softmax denominators
// (no max-sub; logits are O(1) so exp is safe).  Pass 2: alpha-weighted gather
// of xs rows with float4 per lane, register accumulation, relu, store.
// ---------------------------------------------------------------------------
__global__ __launch_bounds__(256) void conv_kernel(
    const float* __restrict__ xs, const float* __restrict__ ss,
    const float* __restrict__ sd, const int* __restrict__ csr_src,
    const int* __restrict__ start, const int* __restrict__ count,
    float* __restrict__ z)
{
  const int dst = blockIdx.x * 4 + (threadIdx.x >> 6);
  const int lane = threadIdx.x & 63;
  const int e0 = start[dst];
  const int ne = count[dst];

  // pass 1: denominators. lane handles head (lane&7), edge stride 8.
  const int h1 = lane & 7;
  const float sdv1 = sd[dst * 8 + h1];
  float den = 0.f;
  for (int j = lane >> 3; j < ne; j += 8) {
    int s = csr_src[e0 + j];
    den += __expf(lrelu(ss[s * 8 + h1] + sdv1));
  }
  den += __shfl_xor(den, 8);
  den += __shfl_xor(den, 16);
  den += __shfl_xor(den, 32);
  // lane l now holds denom for head (l&7); redistribute to head (l>>3)
  const int h2 = lane >> 3;
  const float inv_den = 1.f / (__shfl(den, h2) + 1e-16f);
  const float sdv2 = sd[dst * 8 + h2];

  float a0 = 0.f, a1 = 0.f, a2 = 0.f, a3 = 0.f;
  for (int j = 0; j < ne; ++j) {
    int s = csr_src[e0 + j];
    float alpha = __expf(lrelu(ss[s * 8 + h2] + sdv2)) * inv_den;
    f4 xv = *(const f4*)&xs[(size_t)s * HID + lane * 4];
    a0 = fmaf(alpha, xv.x, a0);
    a1 = fmaf(alpha, xv.y, a1);
    a2 = fmaf(alpha, xv.z, a2);
    a3 = fmaf(alpha, xv.w, a3);
  }
  f4 o = {fmaxf(a0, 0.f), fmaxf(a1, 0.f), fmaxf(a2, 0.f), fmaxf(a3, 0.f)};
  *(f4*)&z[(size_t)dst * HID + lane * 4] = o;
}

// ---------------------------------------------------------------------------
// Semantic scores: score[m] += sum_n sum_hid q[hid]*tanh((z_m@Wk)[n,hid]+bk[hid])
// Both metapaths in one kernel (shared Wk traffic). 16 nodes/block, 4x4x2 tile.
// ---------------------------------------------------------------------------
__global__ __launch_bounds__(256) void semscore_kernel(
    const float* __restrict__ z0, const float* __restrict__ z1,
    const float* __restrict__ Wk, const float* __restrict__ bk,
    const float* __restrict__ q, float* __restrict__ score)
{
  __shared__ float t0[HID * 16];
  __shared__ float t1[HID * 16];
  __shared__ float red[8];
  const int t = threadIdx.x;
  const int base = blockIdx.x * 16;
  for (int idx = t; idx < 16 * HID; idx += 256) {
    int r = idx >> 8, c = idx & (HID - 1);
    t0[c * 16 + r] = z0[(size_t)(base + r) * HID + c];
    t1[c * 16 + r] = z1[(size_t)(base + r) * HID + c];
  }
  __syncthreads();
  const int ig = t >> 6;
  const int j0 = (t & 63) * 4;
  float acc0[4][4] = {};
  float acc1[4][4] = {};
  for (int k = 0; k < HID; ++k) {
    f4 w  = *(const f4*)&Wk[k * HID + j0];
    f4 x0 = *(const f4*)&t0[k * 16 + ig * 4];
    f4 x1 = *(const f4*)&t1[k * 16 + ig * 4];
    const float wa[4] = {w.x, w.y, w.z, w.w};
    const float xa[4] = {x0.x, x0.y, x0.z, x0.w};
    const float ya[4] = {x1.x, x1.y, x1.z, x1.w};
#pragma unroll
    for (int i = 0; i < 4; ++i)
#pragma unroll
      for (int j = 0; j < 4; ++j) {
        acc0[i][j] = fmaf(xa[i], wa[j], acc0[i][j]);
        acc1[i][j] = fmaf(ya[i], wa[j], acc1[i][j]);
      }
  }
  f4 bkv = *(const f4*)&bk[j0];
  f4 qv  = *(const f4*)&q[j0];
  const float bka[4] = {bkv.x, bkv.y, bkv.z, bkv.w};
  const float qa[4]  = {qv.x, qv.y, qv.z, qv.w};
  float s0 = 0.f, s1 = 0.f;
#pragma unroll
  for (int i = 0; i < 4; ++i)
#pragma unroll
    for (int j = 0; j < 4; ++j) {
      s0 += tanhf(acc0[i][j] + bka[j]) * qa[j];
      s1 += tanhf(acc1[i][j] + bka[j]) * qa[j];
    }
  for (int off = 32; off > 0; off >>= 1) {
    s0 += __shfl_down(s0, off);
    s1 += __shfl_down(s1, off);
  }
  const int lane = t & 63;
  const int w = t >> 6;
  if (lane == 0) { red[w] = s0; red[4 + w] = s1; }
  __syncthreads();
  if (t == 0) {
    atomicAdd(&score[0], red[0] + red[1] + red[2] + red[3]);
    atomicAdd(&score[1], red[4] + red[5] + red[6] + red[7]);
  }
}

__global__ void attn_kernel(float* __restrict__ score, float inv_n)
{
  float s0 = score[0] * inv_n, s1 = score[1] * inv_n;
  float m = fmaxf(s0, s1);
  float e0 = __expf(s0 - m), e1 = __expf(s1 - m);
  float d = e0 + e1;
  score[2] = e0 / d;
  score[3] = e1 / d;
}

// ---------------------------------------------------------------------------
// Final: out[n,64] = (a0*z0[n]+a1*z1[n]) @ Wl + bl.  16 rows/block.
// ---------------------------------------------------------------------------
__global__ __launch_bounds__(256) void final_kernel(
    const float* __restrict__ z0, const float* __restrict__ z1,
    const float* __restrict__ attn, const float* __restrict__ Wl,
    const float* __restrict__ bl, float* __restrict__ out)
{
  __shared__ float zT[HID * 16];
  const int t = threadIdx.x;
  const int base = blockIdx.x * 16;
  const float a0 = attn[0], a1 = attn[1];
  for (int idx = t; idx < 16 * HID; idx += 256) {
    int r = idx >> 8, c = idx & (HID - 1);
    zT[c * 16 + r] = a0 * z0[(size_t)(base + r) * HID + c]
                   + a1 * z1[(size_t)(base + r) * HID + c];
  }
  __syncthreads();
  const int ig = t >> 6;
  const int cc = t & 63;
  float acc[4] = {};
  for (int k = 0; k < HID; ++k) {
    float w = Wl[k * OUTD + cc];
    f4 xv = *(const f4*)&zT[k * 16 + ig * 4];
    acc[0] = fmaf(xv.x, w, acc[0]);
    acc[1] = fmaf(xv.y, w, acc[1]);
    acc[2] = fmaf(xv.z, w, acc[2]);
    acc[3] = fmaf(xv.w, w, acc[3]);
  }
  float bb = bl[cc];
#pragma unroll
  for (int i = 0; i < 4; ++i)
    out[(size_t)(base + ig * 4 + i) * OUTD + cc] = acc[i] + bb;
}

// ---------------------------------------------------------------------------
extern "C" void kernel_launch(void* const* d_in, const int* in_sizes, int n_in,
                              void* d_out, int out_size, void* d_ws, size_t ws_size,
                              hipStream_t stream)
{
  const float* x_user = (const float*)d_in[0];
  const float* x_item = (const float*)d_in[1];
  const int*   e_ui   = (const int*)d_in[2];
  const int*   e_iu   = (const int*)d_in[3];
  const int*   e_uu   = (const int*)d_in[4];
  const int*   e_ii   = (const int*)d_in[5];
  const float* Wp_u   = (const float*)d_in[6];
  const float* bp_u   = (const float*)d_in[7];
  const float* Wp_i   = (const float*)d_in[8];
  const float* bp_i   = (const float*)d_in[9];
  const float* as_ui  = (const float*)d_in[10];
  const float* ad_ui  = (const float*)d_in[11];
  const float* as_iu  = (const float*)d_in[12];
  const float* ad_iu  = (const float*)d_in[13];
  const float* as_uu  = (const float*)d_in[14];
  const float* ad_uu  = (const float*)d_in[15];
  const float* as_ii  = (const float*)d_in[16];
  const float* ad_ii  = (const float*)d_in[17];
  const float* Wk     = (const float*)d_in[18];
  const float* bk     = (const float*)d_in[19];
  const float* q      = (const float*)d_in[20];
  const float* Wl     = (const float*)d_in[21];
  const float* bl     = (const float*)d_in[22];

  // workspace layout
  const size_t NH8 = (size_t)N * 8;
  size_t need = ((size_t)4 * N * HID + 8 * NH8 + 4) * sizeof(float)
              + ((size_t)3 * N + E) * sizeof(int);
  if (ws_size < need) {
    // distinctive sentinel so a too-small workspace is diagnosable from absmax
    hipMemsetAsync(d_out, 0x7f, (size_t)out_size * sizeof(float), stream);
    return;
  }
  float* hu = (float*)d_ws;
  float* hi = hu + (size_t)N * HID;
  float* z0 = hi + (size_t)N * HID;
  float* z1 = z0 + (size_t)N * HID;
  float* su = z1 + (size_t)N * HID;   // 4 arrays of N*8
  float* si = su + 4 * NH8;           // 4 arrays of N*8
  float* sc = si + 4 * NH8;           // [s0, s1, attn0, attn1]
  int* count  = (int*)(sc + 4);
  int* start  = count + N;
  int* cursor = start + N;
  int* csr    = cursor + N;

  float* out_u = (float*)d_out;
  float* out_i = out_u + (size_t)N * OUTD;

  // projections
  proj_kernel<<<N / 16, 256, 0, stream>>>(x_user, Wp_u, bp_u, hu);
  proj_kernel<<<N / 16, 256, 0, stream>>>(x_item, Wp_i, bp_i, hi);

  // per-node attention scores (4 per node type, single pass over h each)
  nodescore4_kernel<<<N / 4, 256, 0, stream>>>(hu, ad_iu, as_uu, ad_uu, as_ui,
                                               su, su + NH8, su + 2 * NH8, su + 3 * NH8);
  nodescore4_kernel<<<N / 4, 256, 0, stream>>>(hi, as_iu, ad_ui, as_ii, ad_ii,
                                               si, si + NH8, si + 2 * NH8, si + 3 * NH8);

  auto run_rel = [&](const int* edge, const float* ss, const float* sd,
                     const float* xs, float* zout) {
    hipMemsetAsync(count, 0, N * sizeof(int), stream);
    hist_kernel<<<E / 256, 256, 0, stream>>>(edge + E, count);
    scan_kernel<<<1, 1024, 0, stream>>>(count, start, cursor);
    fill_kernel<<<E / 256, 256, 0, stream>>>(edge, edge + E, cursor, csr);
    conv_kernel<<<N / 4, 256, 0, stream>>>(xs, ss, sd, csr, start, count, zout);
  };

  // ---- user side: metapath 0 = (item->user), metapath 1 = (user->user)
  run_rel(e_iu, si, su, hi, z0);
  run_rel(e_uu, su + NH8, su + 2 * NH8, hu, z1);
  hipMemsetAsync(sc, 0, 2 * sizeof(float), stream);
  semscore_kernel<<<N / 16, 256, 0, stream>>>(z0, z1, Wk, bk, q, sc);
  attn_kernel<<<1, 1, 0, stream>>>(sc, 1.0f / (float)N);
  final_kernel<<<N / 16, 256, 0, stream>>>(z0, z1, sc + 2, Wl, bl, out_u);

  // ---- item side: metapath 0 = (user->item), metapath 1 = (item->item)
  run_rel(e_ui, su + 3 * NH8, si + NH8, hu, z0);
  run_rel(e_ii, si + 2 * NH8, si + 3 * NH8, hi, z1);
  hipMemsetAsync(sc, 0, 2 * sizeof(float), stream);
  semscore_kernel<<<N / 16, 256, 0, stream>>>(z0, z1, Wk, bk, q, sc);
  attn_kernel<<<1, 1, 0, stream>>>(sc, 1.0f / (float)N);
  final_kernel<<<N / 16, 256, 0, stream>>>(z0, z1, sc + 2, Wl, bl, out_i);
}

// Round 2
// 1747.574 us; speedup vs baseline: 1.0921x; 1.0921x over previous
//
#include <hip/hip_runtime.h>
#include <math.h>

#define N     50000
#define F_IN  128
#define HID   256
#define E     800000
#define OUTD  64
#define NEG   0.2f
#define N8    (N * 8)

typedef float4 f4;
typedef unsigned int u32;
typedef unsigned short ush;
typedef float f32x4 __attribute__((ext_vector_type(4)));
typedef short bf16x8 __attribute__((ext_vector_type(8)));

static __device__ __forceinline__ float lrelu(float x) { return x >= 0.f ? x : NEG * x; }
// fp32 -> bf16 round-to-nearest-even
static __device__ __forceinline__ u32 bfr(float x) {
  u32 u = __float_as_uint(x);
  return (u + 0x7fffu + ((u >> 16) & 1u)) >> 16;
}
static __device__ __forceinline__ u32 pk2(float a, float b) { return bfr(a) | (bfr(b) << 16); }
static __device__ __forceinline__ float bf2f(u32 us) { return __uint_as_float(us << 16); }

// ---------------------------------------------------------------------------
// Projection + fused per-node attention scores.
// h[n,256] = x[n,128] @ W + b  (stored bf16); s_k[n,h] = sum_d h[n,h*32+d]*a_k[h*32+d]
// Block = 16 rows; wave ig owns rows ig*4..+3 fully (64 lanes x 4 cols = 256).
// LDS staging uses (r = idx&15) mapping -> conflict-free writes.
// ---------------------------------------------------------------------------
__global__ __launch_bounds__(256) void proj_kernel(
    const float* __restrict__ x, const float* __restrict__ W, const float* __restrict__ b,
    const float* __restrict__ a0, const float* __restrict__ a1,
    const float* __restrict__ a2, const float* __restrict__ a3,
    ush* __restrict__ hb, float* __restrict__ sdst)
{
  __shared__ float xT[F_IN * 16];   // [k][i]
  const int t = threadIdx.x;
  const int base = blockIdx.x * 16;
  for (int idx = t; idx < 16 * F_IN; idx += 256) {
    int r = idx & 15, c = idx >> 4;
    xT[c * 16 + r] = x[(size_t)(base + r) * F_IN + c];
  }
  __syncthreads();
  const int ig = t >> 6;
  const int lane = t & 63;
  const int j0 = lane * 4;
  float acc[4][4] = {};
  for (int k = 0; k < F_IN; ++k) {
    f4 w  = *(const f4*)&W[k * HID + j0];
    f4 xv = *(const f4*)&xT[k * 16 + ig * 4];
    const float wa[4] = {w.x, w.y, w.z, w.w};
    const float xa[4] = {xv.x, xv.y, xv.z, xv.w};
#pragma unroll
    for (int i = 0; i < 4; ++i)
#pragma unroll
      for (int j = 0; j < 4; ++j) acc[i][j] = fmaf(xa[i], wa[j], acc[i][j]);
  }
  f4 bv = *(const f4*)&b[j0];
  const float ba[4] = {bv.x, bv.y, bv.z, bv.w};
#pragma unroll
  for (int i = 0; i < 4; ++i) {
#pragma unroll
    for (int j = 0; j < 4; ++j) acc[i][j] += ba[j];
    ushort4 o;
    o.x = (ush)bfr(acc[i][0]); o.y = (ush)bfr(acc[i][1]);
    o.z = (ush)bfr(acc[i][2]); o.w = (ush)bfr(acc[i][3]);
    *(ushort4*)&hb[(size_t)(base + ig * 4 + i) * HID + j0] = o;
  }
  // fused scores: lane covers head (lane>>3); reduce within 8-lane groups
  const int head = lane >> 3;
  const float* av[4] = {a0, a1, a2, a3};
#pragma unroll
  for (int k = 0; k < 4; ++k) {
    f4 a = *(const f4*)&av[k][j0];
#pragma unroll
    for (int i = 0; i < 4; ++i) {
      float p = acc[i][0] * a.x + acc[i][1] * a.y + acc[i][2] * a.z + acc[i][3] * a.w;
      p += __shfl_xor(p, 1);
      p += __shfl_xor(p, 2);
      p += __shfl_xor(p, 4);
      if ((lane & 7) == 0)
        sdst[(size_t)k * N8 + (size_t)(base + ig * 4 + i) * 8 + head] = p;
    }
  }
}

// ---------------------------------------------------------------------------
// Wk^T bf16 precompute: wkT[n*256+k] = bf16(Wk[k*256+n])
// ---------------------------------------------------------------------------
__global__ void wkt_kernel(const float* __restrict__ Wk, ush* __restrict__ wkT)
{
  int idx = blockIdx.x * 256 + threadIdx.x;
  int n = idx >> 8, k = idx & 255;
  wkT[idx] = (ush)bfr(Wk[k * HID + n]);
}

// ---------------------------------------------------------------------------
// Batched CSR build over 4 relations (segments of count/start/cursor, csr 4E)
// ---------------------------------------------------------------------------
#define EB (E / 256)
__global__ void hist4_kernel(const int* __restrict__ d0, const int* __restrict__ d1,
                             const int* __restrict__ d2, const int* __restrict__ d3,
                             int* __restrict__ count)
{
  int blk = blockIdx.x;
  int rel = blk / EB;
  int i = (blk % EB) * 256 + threadIdx.x;
  const int* dp = rel == 0 ? d0 : rel == 1 ? d1 : rel == 2 ? d2 : d3;
  atomicAdd(&count[rel * N + dp[i]], 1);
}

#define NTOT (4 * N)
__global__ __launch_bounds__(1024) void scan_kernel(
    const int* __restrict__ count, int* __restrict__ start, int* __restrict__ cursor)
{
  __shared__ int part[1024];
  const int t = threadIdx.x;
  const int chunk = (NTOT + 1023) / 1024;
  const int b = t * chunk;
  const int e = min(NTOT, b + chunk);
  int s = 0;
  for (int i = b; i < e; ++i) s += count[i];
  part[t] = s;
  __syncthreads();
  for (int off = 1; off < 1024; off <<= 1) {
    int v = (t >= off) ? part[t - off] : 0;
    __syncthreads();
    part[t] += v;
    __syncthreads();
  }
  int run = (t == 0) ? 0 : part[t - 1];
  for (int i = b; i < e; ++i) {
    start[i] = run;
    cursor[i] = run;
    run += count[i];
  }
}

__global__ void fill4_kernel(const int* __restrict__ s0, const int* __restrict__ d0,
                             const int* __restrict__ s1, const int* __restrict__ d1,
                             const int* __restrict__ s2, const int* __restrict__ d2,
                             const int* __restrict__ s3, const int* __restrict__ d3,
                             int* __restrict__ cursor, int* __restrict__ csr)
{
  int blk = blockIdx.x;
  int rel = blk / EB;
  int i = (blk % EB) * 256 + threadIdx.x;
  const int* sp = rel == 0 ? s0 : rel == 1 ? s1 : rel == 2 ? s2 : s3;
  const int* dp = rel == 0 ? d0 : rel == 1 ? d1 : rel == 2 ? d2 : d3;
  int pos = atomicAdd(&cursor[rel * N + dp[i]], 1);
  csr[pos] = sp[i];
}

// ---------------------------------------------------------------------------
// Relation conv, bf16 row gathers (512B/edge), fp32 accumulate, 2-edge unroll.
// ---------------------------------------------------------------------------
__global__ __launch_bounds__(256) void conv_kernel(
    const ush* __restrict__ xsb, const float* __restrict__ ss,
    const float* __restrict__ sd, const int* __restrict__ csr,
    const int* __restrict__ start, const int* __restrict__ count,
    float* __restrict__ z)
{
  const int dst = blockIdx.x * 4 + (threadIdx.x >> 6);
  const int lane = threadIdx.x & 63;
  const int e0 = start[dst];
  const int ne = count[dst];

  const int h1 = lane & 7;
  const float sdv1 = sd[dst * 8 + h1];
  float den = 0.f;
  for (int j = lane >> 3; j < ne; j += 8)
    den += __expf(lrelu(ss[csr[e0 + j] * 8 + h1] + sdv1));
  den += __shfl_xor(den, 8);
  den += __shfl_xor(den, 16);
  den += __shfl_xor(den, 32);
  const int h2 = lane >> 3;
  const float inv_den = 1.f / (__shfl(den, h2) + 1e-16f);
  const float sdv2 = sd[dst * 8 + h2];

  float a0 = 0.f, a1 = 0.f, a2 = 0.f, a3 = 0.f;
  int j = 0;
  for (; j + 2 <= ne; j += 2) {
    int sA = csr[e0 + j], sB = csr[e0 + j + 1];
    float lA = ss[sA * 8 + h2], lB = ss[sB * 8 + h2];
    ushort4 vA = *(const ushort4*)&xsb[(size_t)sA * HID + lane * 4];
    ushort4 vB = *(const ushort4*)&xsb[(size_t)sB * HID + lane * 4];
    float alA = __expf(lrelu(lA + sdv2)) * inv_den;
    float alB = __expf(lrelu(lB + sdv2)) * inv_den;
    a0 = fmaf(alA, bf2f(vA.x), a0);
    a1 = fmaf(alA, bf2f(vA.y), a1);
    a2 = fmaf(alA, bf2f(vA.z), a2);
    a3 = fmaf(alA, bf2f(vA.w), a3);
    a0 = fmaf(alB, bf2f(vB.x), a0);
    a1 = fmaf(alB, bf2f(vB.y), a1);
    a2 = fmaf(alB, bf2f(vB.z), a2);
    a3 = fmaf(alB, bf2f(vB.w), a3);
  }
  if (j < ne) {
    int sA = csr[e0 + j];
    float alA = __expf(lrelu(ss[sA * 8 + h2] + sdv2)) * inv_den;
    ushort4 vA = *(const ushort4*)&xsb[(size_t)sA * HID + lane * 4];
    a0 = fmaf(alA, bf2f(vA.x), a0);
    a1 = fmaf(alA, bf2f(vA.y), a1);
    a2 = fmaf(alA, bf2f(vA.z), a2);
    a3 = fmaf(alA, bf2f(vA.w), a3);
  }
  f4 o = {fmaxf(a0, 0.f), fmaxf(a1, 0.f), fmaxf(a2, 0.f), fmaxf(a3, 0.f)};
  *(f4*)&z[(size_t)dst * HID + lane * 4] = o;
}

// ---------------------------------------------------------------------------
// Semantic scores via bf16 MFMA 16x16x32.  Block = 64 rows (4 waves x 16),
// N=256 (16 n-tiles), K=256 in 4 chunks of 64.  Wk^T staged to LDS with XOR
// swizzle ((row&7)<<4 bytes) so stride-128B fragment reads are conflict-free.
// score[m] += sum_{rows,cols} q[col]*tanh((z_m@Wk)[row,col]+bk[col])
// ---------------------------------------------------------------------------
__global__ __launch_bounds__(256) void semscore_kernel(
    const float* __restrict__ z0, const float* __restrict__ z1,
    const ush* __restrict__ wkT, const float* __restrict__ bk,
    const float* __restrict__ q, float* __restrict__ score)
{
  __shared__ u32 Bs[8192];   // WkT chunk [n=256][k=64] bf16, swizzled
  __shared__ u32 As0[2048];  // z0 tile  [r=64][k=64] bf16, swizzled
  __shared__ u32 As1[2048];
  const int t = threadIdx.x;
  const int base = blockIdx.x * 64;
  const int w = t >> 6;
  const int l = t & 63;
  const int lrow = l & 15;
  const int kgrp = l >> 4;

  f32x4 acc0[16], acc1[16];
  const f32x4 zz = {0.f, 0.f, 0.f, 0.f};
#pragma unroll
  for (int nt = 0; nt < 16; ++nt) { acc0[nt] = zz; acc1[nt] = zz; }

  for (int kc = 0; kc < 4; ++kc) {
    // stage Bs: 2048 16B-chunks
#pragma unroll
    for (int it = 0; it < 8; ++it) {
      int cid = it * 256 + t;
      int n = cid >> 3, g = cid & 7;
      uint4 v = *(const uint4*)&wkT[n * HID + kc * 64 + g * 8];
      *(uint4*)&Bs[(n * 32 + g * 4) ^ ((n & 7) << 2)] = v;
    }
    // stage As0/As1 with fp32->bf16 conversion
#pragma unroll
    for (int m = 0; m < 2; ++m) {
      const float* zp = m ? z1 : z0;
      u32* ap = m ? As1 : As0;
#pragma unroll
      for (int it = 0; it < 2; ++it) {
        int cid = it * 256 + t;
        int r = cid >> 3, g = cid & 7;
        int gr = base + r;
        if (gr >= N) gr = N - 1;  // clamped rows masked in epilogue
        const float* sp = &zp[(size_t)gr * HID + kc * 64 + g * 8];
        f4 v0 = *(const f4*)sp;
        f4 v1 = *(const f4*)(sp + 4);
        int di = (r * 32 + g * 4) ^ ((r & 7) << 2);
        ap[di + 0] = pk2(v0.x, v0.y);
        ap[di + 1] = pk2(v0.z, v0.w);
        ap[di + 2] = pk2(v1.x, v1.y);
        ap[di + 3] = pk2(v1.z, v1.w);
      }
    }
    __syncthreads();
#pragma unroll
    for (int kk = 0; kk < 2; ++kk) {
      int ai = ((w * 16 + lrow) * 32 + kk * 16 + kgrp * 4) ^ ((lrow & 7) << 2);
      bf16x8 af0 = *(const bf16x8*)&As0[ai];
      bf16x8 af1 = *(const bf16x8*)&As1[ai];
#pragma unroll
      for (int nt = 0; nt < 16; ++nt) {
        int n = nt * 16 + lrow;
        int bi = (n * 32 + kk * 16 + kgrp * 4) ^ ((n & 7) << 2);
        bf16x8 bf = *(const bf16x8*)&Bs[bi];
        acc0[nt] = __builtin_amdgcn_mfma_f32_16x16x32_bf16(af0, bf, acc0[nt], 0, 0, 0);
        acc1[nt] = __builtin_amdgcn_mfma_f32_16x16x32_bf16(af1, bf, acc1[nt], 0, 0, 0);
      }
    }
    __syncthreads();
  }

  // epilogue: D row = kgrp*4+i (local), col = nt*16 + lrow
  float s0 = 0.f, s1 = 0.f;
#pragma unroll
  for (int nt = 0; nt < 16; ++nt) {
    int col = nt * 16 + lrow;
    float bkv = bk[col], qv = q[col];
#pragma unroll
    for (int i = 0; i < 4; ++i) {
      int gr = base + w * 16 + kgrp * 4 + i;
      if (gr < N) {
        s0 += tanhf(acc0[nt][i] + bkv) * qv;
        s1 += tanhf(acc1[nt][i] + bkv) * qv;
      }
    }
  }
#pragma unroll
  for (int off = 1; off < 64; off <<= 1) {
    s0 += __shfl_xor(s0, off);
    s1 += __shfl_xor(s1, off);
  }
  if (l == 0) {
    atomicAdd(&score[0], s0);
    atomicAdd(&score[1], s1);
  }
}

__global__ void attn_kernel(float* __restrict__ score, float inv_n)
{
  float s0 = score[0] * inv_n, s1 = score[1] * inv_n;
  float m = fmaxf(s0, s1);
  float e0 = __expf(s0 - m), e1 = __expf(s1 - m);
  float d = e0 + e1;
  score[2] = e0 / d;
  score[3] = e1 / d;
}

// ---------------------------------------------------------------------------
// Final: out[n,64] = (a0*z0[n]+a1*z1[n]) @ Wl + bl.  16 rows/block.
// Staging uses (r = idx&15) mapping -> conflict-free LDS writes.
// ---------------------------------------------------------------------------
__global__ __launch_bounds__(256) void final_kernel(
    const float* __restrict__ z0, const float* __restrict__ z1,
    const float* __restrict__ attn, const float* __restrict__ Wl,
    const float* __restrict__ bl, float* __restrict__ out)
{
  __shared__ float zT[HID * 16];
  const int t = threadIdx.x;
  const int base = blockIdx.x * 16;
  const float a0 = attn[0], a1 = attn[1];
  for (int idx = t; idx < 16 * HID; idx += 256) {
    int r = idx & 15, c = idx >> 4;
    zT[c * 16 + r] = a0 * z0[(size_t)(base + r) * HID + c]
                   + a1 * z1[(size_t)(base + r) * HID + c];
  }
  __syncthreads();
  const int ig = t >> 6;
  const int cc = t & 63;
  float acc[4] = {};
  for (int k = 0; k < HID; ++k) {
    float w = Wl[k * OUTD + cc];
    f4 xv = *(const f4*)&zT[k * 16 + ig * 4];
    acc[0] = fmaf(xv.x, w, acc[0]);
    acc[1] = fmaf(xv.y, w, acc[1]);
    acc[2] = fmaf(xv.z, w, acc[2]);
    acc[3] = fmaf(xv.w, w, acc[3]);
  }
  float bb = bl[cc];
#pragma unroll
  for (int i = 0; i < 4; ++i)
    out[(size_t)(base + ig * 4 + i) * OUTD + cc] = acc[i] + bb;
}

// ---------------------------------------------------------------------------
extern "C" void kernel_launch(void* const* d_in, const int* in_sizes, int n_in,
                              void* d_out, int out_size, void* d_ws, size_t ws_size,
                              hipStream_t stream)
{
  const float* x_user = (const float*)d_in[0];
  const float* x_item = (const float*)d_in[1];
  const int*   e_ui   = (const int*)d_in[2];
  const int*   e_iu   = (const int*)d_in[3];
  const int*   e_uu   = (const int*)d_in[4];
  const int*   e_ii   = (const int*)d_in[5];
  const float* Wp_u   = (const float*)d_in[6];
  const float* bp_u   = (const float*)d_in[7];
  const float* Wp_i   = (const float*)d_in[8];
  const float* bp_i   = (const float*)d_in[9];
  const float* as_ui  = (const float*)d_in[10];
  const float* ad_ui  = (const float*)d_in[11];
  const float* as_iu  = (const float*)d_in[12];
  const float* ad_iu  = (const float*)d_in[13];
  const float* as_uu  = (const float*)d_in[14];
  const float* ad_uu  = (const float*)d_in[15];
  const float* as_ii  = (const float*)d_in[16];
  const float* ad_ii  = (const float*)d_in[17];
  const float* Wk     = (const float*)d_in[18];
  const float* bk     = (const float*)d_in[19];
  const float* q      = (const float*)d_in[20];
  const float* Wl     = (const float*)d_in[21];
  const float* bl     = (const float*)d_in[22];

  const size_t NH = (size_t)N * HID;
  size_t need = (2 * NH + 8 * (size_t)N8 + 4) * 4   // z0,z1,su,si,sc (f32)
              + (2 * NH + HID * HID) * 2            // hub,hib,wkT (bf16)
              + ((size_t)12 * N + 4 * (size_t)E) * 4; // count/start/cursor + csr
  if (ws_size < need) {
    hipMemsetAsync(d_out, 0x7f, (size_t)out_size * sizeof(float), stream);
    return;
  }
  float* z0 = (float*)d_ws;
  float* z1 = z0 + NH;
  float* su = z1 + NH;
  float* si = su + 4 * (size_t)N8;
  float* sc = si + 4 * (size_t)N8;
  ush* hub  = (ush*)(sc + 4);
  ush* hib  = hub + NH;
  ush* wkT  = hib + NH;
  int* count  = (int*)(wkT + HID * HID);
  int* start  = count + NTOT;
  int* cursor = start + NTOT;
  int* csr    = cursor + NTOT;

  float* out_u = (float*)d_out;
  float* out_i = out_u + (size_t)N * OUTD;

  wkt_kernel<<<HID * HID / 256, 256, 0, stream>>>(Wk, wkT);

  // projections with fused node scores
  proj_kernel<<<N / 16, 256, 0, stream>>>(x_user, Wp_u, bp_u,
                                          ad_iu, as_uu, ad_uu, as_ui, hub, su);
  proj_kernel<<<N / 16, 256, 0, stream>>>(x_item, Wp_i, bp_i,
                                          as_iu, ad_ui, as_ii, ad_ii, hib, si);

  // batched CSR build: rel 0=iu, 1=uu, 2=ui, 3=ii
  hipMemsetAsync(count, 0, NTOT * sizeof(int), stream);
  hist4_kernel<<<4 * EB, 256, 0, stream>>>(e_iu + E, e_uu + E, e_ui + E, e_ii + E, count);
  scan_kernel<<<1, 1024, 0, stream>>>(count, start, cursor);
  fill4_kernel<<<4 * EB, 256, 0, stream>>>(e_iu, e_iu + E, e_uu, e_uu + E,
                                           e_ui, e_ui + E, e_ii, e_ii + E, cursor, csr);

  const int SEMG = (N + 63) / 64;

  // ---- user side: metapath 0 = (item->user), metapath 1 = (user->user)
  conv_kernel<<<N / 4, 256, 0, stream>>>(hib, si, su, csr, start, count, z0);
  conv_kernel<<<N / 4, 256, 0, stream>>>(hub, su + N8, su + 2 * (size_t)N8, csr,
                                         start + N, count + N, z1);
  hipMemsetAsync(sc, 0, 2 * sizeof(float), stream);
  semscore_kernel<<<SEMG, 256, 0, stream>>>(z0, z1, wkT, bk, q, sc);
  attn_kernel<<<1, 1, 0, stream>>>(sc, 1.0f / (float)N);
  final_kernel<<<N / 16, 256, 0, stream>>>(z0, z1, sc + 2, Wl, bl, out_u);

  // ---- item side: metapath 0 = (user->item), metapath 1 = (item->item)
  conv_kernel<<<N / 4, 256, 0, stream>>>(hub, su + 3 * (size_t)N8, si + N8, csr,
                                         start + 2 * N, count + 2 * N, z0);
  conv_kernel<<<N / 4, 256, 0, stream>>>(hib, si + 2 * (size_t)N8, si + 3 * (size_t)N8, csr,
                                         start + 3 * N, count + 3 * N, z1);
  hipMemsetAsync(sc, 0, 2 * sizeof(float), stream);
  semscore_kernel<<<SEMG, 256, 0, stream>>>(z0, z1, wkT, bk, q, sc);
  attn_kernel<<<1, 1, 0, stream>>>(sc, 1.0f / (float)N);
  final_kernel<<<N / 16, 256, 0, stream>>>(z0, z1, sc + 2, Wl, bl, out_i);
}

// Round 3
// 1306.477 us; speedup vs baseline: 1.4608x; 1.3376x over previous
//
#include <hip/hip_runtime.h>
#include <math.h>

#define N     50000
#define F_IN  128
#define HID   256
#define E     800000
#define OUTD  64
#define NEG   0.2f
#define N8    (N * 8)
#define NTOT  (4 * N)

// hierarchical scan geometry
#define SC_TPB   256
#define SC_PERB  2048                       // 256 threads x 8 elems
#define SC_NB    ((NTOT + SC_PERB - 1) / SC_PERB)   // 98

typedef float4 f4;
typedef unsigned int u32;
typedef unsigned short ush;
typedef float f32x4 __attribute__((ext_vector_type(4)));
typedef short bf16x8 __attribute__((ext_vector_type(8)));

static __device__ __forceinline__ float lrelu(float x) { return x >= 0.f ? x : NEG * x; }
// fp32 -> bf16 round-to-nearest-even
static __device__ __forceinline__ u32 bfr(float x) {
  u32 u = __float_as_uint(x);
  return (u + 0x7fffu + ((u >> 16) & 1u)) >> 16;
}
static __device__ __forceinline__ u32 pk2(float a, float b) { return bfr(a) | (bfr(b) << 16); }
static __device__ __forceinline__ float bf2f(u32 us) { return __uint_as_float(us << 16); }

// ---------------------------------------------------------------------------
// Projection + fused per-node attention scores.
// ---------------------------------------------------------------------------
__global__ __launch_bounds__(256) void proj_kernel(
    const float* __restrict__ x, const float* __restrict__ W, const float* __restrict__ b,
    const float* __restrict__ a0, const float* __restrict__ a1,
    const float* __restrict__ a2, const float* __restrict__ a3,
    ush* __restrict__ hb, float* __restrict__ sdst)
{
  __shared__ float xT[F_IN * 16];   // [k][i]
  const int t = threadIdx.x;
  const int base = blockIdx.x * 16;
  for (int idx = t; idx < 16 * F_IN; idx += 256) {
    int r = idx & 15, c = idx >> 4;
    xT[c * 16 + r] = x[(size_t)(base + r) * F_IN + c];
  }
  __syncthreads();
  const int ig = t >> 6;
  const int lane = t & 63;
  const int j0 = lane * 4;
  float acc[4][4] = {};
  for (int k = 0; k < F_IN; ++k) {
    f4 w  = *(const f4*)&W[k * HID + j0];
    f4 xv = *(const f4*)&xT[k * 16 + ig * 4];
    const float wa[4] = {w.x, w.y, w.z, w.w};
    const float xa[4] = {xv.x, xv.y, xv.z, xv.w};
#pragma unroll
    for (int i = 0; i < 4; ++i)
#pragma unroll
      for (int j = 0; j < 4; ++j) acc[i][j] = fmaf(xa[i], wa[j], acc[i][j]);
  }
  f4 bv = *(const f4*)&b[j0];
  const float ba[4] = {bv.x, bv.y, bv.z, bv.w};
#pragma unroll
  for (int i = 0; i < 4; ++i) {
#pragma unroll
    for (int j = 0; j < 4; ++j) acc[i][j] += ba[j];
    ushort4 o;
    o.x = (ush)bfr(acc[i][0]); o.y = (ush)bfr(acc[i][1]);
    o.z = (ush)bfr(acc[i][2]); o.w = (ush)bfr(acc[i][3]);
    *(ushort4*)&hb[(size_t)(base + ig * 4 + i) * HID + j0] = o;
  }
  const int head = lane >> 3;
  const float* av[4] = {a0, a1, a2, a3};
#pragma unroll
  for (int k = 0; k < 4; ++k) {
    f4 a = *(const f4*)&av[k][j0];
#pragma unroll
    for (int i = 0; i < 4; ++i) {
      float p = acc[i][0] * a.x + acc[i][1] * a.y + acc[i][2] * a.z + acc[i][3] * a.w;
      p += __shfl_xor(p, 1);
      p += __shfl_xor(p, 2);
      p += __shfl_xor(p, 4);
      if ((lane & 7) == 0)
        sdst[(size_t)k * N8 + (size_t)(base + ig * 4 + i) * 8 + head] = p;
    }
  }
}

// ---------------------------------------------------------------------------
__global__ void wkt_kernel(const float* __restrict__ Wk, ush* __restrict__ wkT)
{
  int idx = blockIdx.x * 256 + threadIdx.x;
  int n = idx >> 8, k = idx & 255;
  wkT[idx] = (ush)bfr(Wk[k * HID + n]);
}

// ---------------------------------------------------------------------------
// Batched CSR build over 4 relations
// ---------------------------------------------------------------------------
#define EB (E / 256)
__global__ void hist4_kernel(const int* __restrict__ d0, const int* __restrict__ d1,
                             const int* __restrict__ d2, const int* __restrict__ d3,
                             int* __restrict__ count)
{
  int blk = blockIdx.x;
  int rel = blk / EB;
  int i = (blk % EB) * 256 + threadIdx.x;
  const int* dp = rel == 0 ? d0 : rel == 1 ? d1 : rel == 2 ? d2 : d3;
  atomicAdd(&count[rel * N + dp[i]], 1);
}

// 3-phase hierarchical exclusive scan of count[NTOT] -> start, cursor
__global__ __launch_bounds__(SC_TPB) void scanA_kernel(
    const int* __restrict__ count, int* __restrict__ bsum)
{
  __shared__ int red[4];
  const int t = threadIdx.x;
  const int base = blockIdx.x * SC_PERB + t * 8;
  int s = 0;
  if (base + 8 <= NTOT) {
    int4 a = *(const int4*)&count[base];
    int4 b = *(const int4*)&count[base + 4];
    s = a.x + a.y + a.z + a.w + b.x + b.y + b.z + b.w;
  } else {
    for (int i = 0; i < 8; ++i) { int idx = base + i; if (idx < NTOT) s += count[idx]; }
  }
#pragma unroll
  for (int off = 1; off < 64; off <<= 1) s += __shfl_xor(s, off);
  if ((t & 63) == 0) red[t >> 6] = s;
  __syncthreads();
  if (t == 0) bsum[blockIdx.x] = red[0] + red[1] + red[2] + red[3];
}

__global__ __launch_bounds__(128) void scanB_kernel(int* __restrict__ bsum)
{
  __shared__ int tmp[128];
  const int t = threadIdx.x;
  int v = (t < SC_NB) ? bsum[t] : 0;
  tmp[t] = v;
  __syncthreads();
  for (int off = 1; off < 128; off <<= 1) {
    int u = (t >= off) ? tmp[t - off] : 0;
    __syncthreads();
    tmp[t] += u;
    __syncthreads();
  }
  if (t < SC_NB) bsum[t] = tmp[t] - v;  // exclusive
}

__global__ __launch_bounds__(SC_TPB) void scanC_kernel(
    const int* __restrict__ count, const int* __restrict__ bsum,
    int* __restrict__ start, int* __restrict__ cursor)
{
  __shared__ int ts[SC_TPB];
  const int t = threadIdx.x;
  const int base = blockIdx.x * SC_PERB + t * 8;
  int c[8];
  int s = 0;
#pragma unroll
  for (int i = 0; i < 8; ++i) {
    int idx = base + i;
    c[i] = (idx < NTOT) ? count[idx] : 0;
    s += c[i];
  }
  ts[t] = s;
  __syncthreads();
  for (int off = 1; off < SC_TPB; off <<= 1) {
    int u = (t >= off) ? ts[t - off] : 0;
    __syncthreads();
    ts[t] += u;
    __syncthreads();
  }
  int run = ts[t] - s + bsum[blockIdx.x];
#pragma unroll
  for (int i = 0; i < 8; ++i) {
    int idx = base + i;
    if (idx < NTOT) {
      start[idx] = run;
      cursor[idx] = run;
      run += c[i];
    }
  }
}

__global__ void fill4_kernel(const int* __restrict__ s0, const int* __restrict__ d0,
                             const int* __restrict__ s1, const int* __restrict__ d1,
                             const int* __restrict__ s2, const int* __restrict__ d2,
                             const int* __restrict__ s3, const int* __restrict__ d3,
                             int* __restrict__ cursor, int* __restrict__ csr)
{
  int blk = blockIdx.x;
  int rel = blk / EB;
  int i = (blk % EB) * 256 + threadIdx.x;
  const int* sp = rel == 0 ? s0 : rel == 1 ? s1 : rel == 2 ? s2 : s3;
  const int* dp = rel == 0 ? d0 : rel == 1 ? d1 : rel == 2 ? d2 : d3;
  int pos = atomicAdd(&cursor[rel * N + dp[i]], 1);
  csr[pos] = sp[i];
}

// ---------------------------------------------------------------------------
// Relation conv, bf16 row gathers (512B/edge), fp32 accumulate, 2-edge unroll.
// ---------------------------------------------------------------------------
__global__ __launch_bounds__(256) void conv_kernel(
    const ush* __restrict__ xsb, const float* __restrict__ ss,
    const float* __restrict__ sd, const int* __restrict__ csr,
    const int* __restrict__ start, const int* __restrict__ count,
    float* __restrict__ z)
{
  const int dst = blockIdx.x * 4 + (threadIdx.x >> 6);
  const int lane = threadIdx.x & 63;
  const int e0 = start[dst];
  const int ne = count[dst];

  const int h1 = lane & 7;
  const float sdv1 = sd[dst * 8 + h1];
  float den = 0.f;
  for (int j = lane >> 3; j < ne; j += 8)
    den += __expf(lrelu(ss[csr[e0 + j] * 8 + h1] + sdv1));
  den += __shfl_xor(den, 8);
  den += __shfl_xor(den, 16);
  den += __shfl_xor(den, 32);
  const int h2 = lane >> 3;
  const float inv_den = 1.f / (__shfl(den, h2) + 1e-16f);
  const float sdv2 = sd[dst * 8 + h2];

  float a0 = 0.f, a1 = 0.f, a2 = 0.f, a3 = 0.f;
  int j = 0;
  for (; j + 2 <= ne; j += 2) {
    int sA = csr[e0 + j], sB = csr[e0 + j + 1];
    float lA = ss[sA * 8 + h2], lB = ss[sB * 8 + h2];
    ushort4 vA = *(const ushort4*)&xsb[(size_t)sA * HID + lane * 4];
    ushort4 vB = *(const ushort4*)&xsb[(size_t)sB * HID + lane * 4];
    float alA = __expf(lrelu(lA + sdv2)) * inv_den;
    float alB = __expf(lrelu(lB + sdv2)) * inv_den;
    a0 = fmaf(alA, bf2f(vA.x), a0);
    a1 = fmaf(alA, bf2f(vA.y), a1);
    a2 = fmaf(alA, bf2f(vA.z), a2);
    a3 = fmaf(alA, bf2f(vA.w), a3);
    a0 = fmaf(alB, bf2f(vB.x), a0);
    a1 = fmaf(alB, bf2f(vB.y), a1);
    a2 = fmaf(alB, bf2f(vB.z), a2);
    a3 = fmaf(alB, bf2f(vB.w), a3);
  }
  if (j < ne) {
    int sA = csr[e0 + j];
    float alA = __expf(lrelu(ss[sA * 8 + h2] + sdv2)) * inv_den;
    ushort4 vA = *(const ushort4*)&xsb[(size_t)sA * HID + lane * 4];
    a0 = fmaf(alA, bf2f(vA.x), a0);
    a1 = fmaf(alA, bf2f(vA.y), a1);
    a2 = fmaf(alA, bf2f(vA.z), a2);
    a3 = fmaf(alA, bf2f(vA.w), a3);
  }
  f4 o = {fmaxf(a0, 0.f), fmaxf(a1, 0.f), fmaxf(a2, 0.f), fmaxf(a3, 0.f)};
  *(f4*)&z[(size_t)dst * HID + lane * 4] = o;
}

// ---------------------------------------------------------------------------
// Semantic scores via bf16 MFMA 16x16x32 (see R2 notes).
// ---------------------------------------------------------------------------
__global__ __launch_bounds__(256) void semscore_kernel(
    const float* __restrict__ z0, const float* __restrict__ z1,
    const ush* __restrict__ wkT, const float* __restrict__ bk,
    const float* __restrict__ q, float* __restrict__ score)
{
  __shared__ u32 Bs[8192];   // WkT chunk [n=256][k=64] bf16, swizzled
  __shared__ u32 As0[2048];  // z tile [r=64][k=64] bf16, swizzled
  __shared__ u32 As1[2048];
  const int t = threadIdx.x;
  const int base = blockIdx.x * 64;
  const int w = t >> 6;
  const int l = t & 63;
  const int lrow = l & 15;
  const int kgrp = l >> 4;

  f32x4 acc0[16], acc1[16];
  const f32x4 zz = {0.f, 0.f, 0.f, 0.f};
#pragma unroll
  for (int nt = 0; nt < 16; ++nt) { acc0[nt] = zz; acc1[nt] = zz; }

  for (int kc = 0; kc < 4; ++kc) {
#pragma unroll
    for (int it = 0; it < 8; ++it) {
      int cid = it * 256 + t;
      int n = cid >> 3, g = cid & 7;
      uint4 v = *(const uint4*)&wkT[n * HID + kc * 64 + g * 8];
      *(uint4*)&Bs[(n * 32 + g * 4) ^ ((n & 7) << 2)] = v;
    }
#pragma unroll
    for (int m = 0; m < 2; ++m) {
      const float* zp = m ? z1 : z0;
      u32* ap = m ? As1 : As0;
#pragma unroll
      for (int it = 0; it < 2; ++it) {
        int cid = it * 256 + t;
        int r = cid >> 3, g = cid & 7;
        int gr = base + r;
        if (gr >= N) gr = N - 1;
        const float* sp = &zp[(size_t)gr * HID + kc * 64 + g * 8];
        f4 v0 = *(const f4*)sp;
        f4 v1 = *(const f4*)(sp + 4);
        int di = (r * 32 + g * 4) ^ ((r & 7) << 2);
        ap[di + 0] = pk2(v0.x, v0.y);
        ap[di + 1] = pk2(v0.z, v0.w);
        ap[di + 2] = pk2(v1.x, v1.y);
        ap[di + 3] = pk2(v1.z, v1.w);
      }
    }
    __syncthreads();
#pragma unroll
    for (int kk = 0; kk < 2; ++kk) {
      int ai = ((w * 16 + lrow) * 32 + kk * 16 + kgrp * 4) ^ ((lrow & 7) << 2);
      bf16x8 af0 = *(const bf16x8*)&As0[ai];
      bf16x8 af1 = *(const bf16x8*)&As1[ai];
#pragma unroll
      for (int nt = 0; nt < 16; ++nt) {
        int n = nt * 16 + lrow;
        int bi = (n * 32 + kk * 16 + kgrp * 4) ^ ((n & 7) << 2);
        bf16x8 bf = *(const bf16x8*)&Bs[bi];
        acc0[nt] = __builtin_amdgcn_mfma_f32_16x16x32_bf16(af0, bf, acc0[nt], 0, 0, 0);
        acc1[nt] = __builtin_amdgcn_mfma_f32_16x16x32_bf16(af1, bf, acc1[nt], 0, 0, 0);
      }
    }
    __syncthreads();
  }

  float s0 = 0.f, s1 = 0.f;
#pragma unroll
  for (int nt = 0; nt < 16; ++nt) {
    int col = nt * 16 + lrow;
    float bkv = bk[col], qv = q[col];
#pragma unroll
    for (int i = 0; i < 4; ++i) {
      int gr = base + w * 16 + kgrp * 4 + i;
      if (gr < N) {
        s0 += tanhf(acc0[nt][i] + bkv) * qv;
        s1 += tanhf(acc1[nt][i] + bkv) * qv;
      }
    }
  }
#pragma unroll
  for (int off = 1; off < 64; off <<= 1) {
    s0 += __shfl_xor(s0, off);
    s1 += __shfl_xor(s1, off);
  }
  if (l == 0) {
    atomicAdd(&score[0], s0);
    atomicAdd(&score[1], s1);
  }
}

__global__ void attn_kernel(float* __restrict__ score, float inv_n)
{
  float s0 = score[0] * inv_n, s1 = score[1] * inv_n;
  float m = fmaxf(s0, s1);
  float e0 = __expf(s0 - m), e1 = __expf(s1 - m);
  float d = e0 + e1;
  score[2] = e0 / d;
  score[3] = e1 / d;
}

// ---------------------------------------------------------------------------
__global__ __launch_bounds__(256) void final_kernel(
    const float* __restrict__ z0, const float* __restrict__ z1,
    const float* __restrict__ attn, const float* __restrict__ Wl,
    const float* __restrict__ bl, float* __restrict__ out)
{
  __shared__ float zT[HID * 16];
  const int t = threadIdx.x;
  const int base = blockIdx.x * 16;
  const float a0 = attn[0], a1 = attn[1];
  for (int idx = t; idx < 16 * HID; idx += 256) {
    int r = idx & 15, c = idx >> 4;
    zT[c * 16 + r] = a0 * z0[(size_t)(base + r) * HID + c]
                   + a1 * z1[(size_t)(base + r) * HID + c];
  }
  __syncthreads();
  const int ig = t >> 6;
  const int cc = t & 63;
  float acc[4] = {};
  for (int k = 0; k < HID; ++k) {
    float w = Wl[k * OUTD + cc];
    f4 xv = *(const f4*)&zT[k * 16 + ig * 4];
    acc[0] = fmaf(xv.x, w, acc[0]);
    acc[1] = fmaf(xv.y, w, acc[1]);
    acc[2] = fmaf(xv.z, w, acc[2]);
    acc[3] = fmaf(xv.w, w, acc[3]);
  }
  float bb = bl[cc];
#pragma unroll
  for (int i = 0; i < 4; ++i)
    out[(size_t)(base + ig * 4 + i) * OUTD + cc] = acc[i] + bb;
}

// ---------------------------------------------------------------------------
extern "C" void kernel_launch(void* const* d_in, const int* in_sizes, int n_in,
                              void* d_out, int out_size, void* d_ws, size_t ws_size,
                              hipStream_t stream)
{
  const float* x_user = (const float*)d_in[0];
  const float* x_item = (const float*)d_in[1];
  const int*   e_ui   = (const int*)d_in[2];
  const int*   e_iu   = (const int*)d_in[3];
  const int*   e_uu   = (const int*)d_in[4];
  const int*   e_ii   = (const int*)d_in[5];
  const float* Wp_u   = (const float*)d_in[6];
  const float* bp_u   = (const float*)d_in[7];
  const float* Wp_i   = (const float*)d_in[8];
  const float* bp_i   = (const float*)d_in[9];
  const float* as_ui  = (const float*)d_in[10];
  const float* ad_ui  = (const float*)d_in[11];
  const float* as_iu  = (const float*)d_in[12];
  const float* ad_iu  = (const float*)d_in[13];
  const float* as_uu  = (const float*)d_in[14];
  const float* ad_uu  = (const float*)d_in[15];
  const float* as_ii  = (const float*)d_in[16];
  const float* ad_ii  = (const float*)d_in[17];
  const float* Wk     = (const float*)d_in[18];
  const float* bk     = (const float*)d_in[19];
  const float* q      = (const float*)d_in[20];
  const float* Wl     = (const float*)d_in[21];
  const float* bl     = (const float*)d_in[22];

  const size_t NH = (size_t)N * HID;
  size_t need = (2 * NH + 8 * (size_t)N8 + 4) * 4       // z0,z1,su,si,sc
              + (2 * NH + HID * HID) * 2                // hub,hib,wkT
              + ((size_t)12 * N + 4 * (size_t)E + 128) * 4; // count/start/cursor + csr + bsum
  if (ws_size < need) {
    hipMemsetAsync(d_out, 0x7f, (size_t)out_size * sizeof(float), stream);
    return;
  }
  float* z0 = (float*)d_ws;
  float* z1 = z0 + NH;
  float* su = z1 + NH;
  float* si = su + 4 * (size_t)N8;
  float* sc = si + 4 * (size_t)N8;
  ush* hub  = (ush*)(sc + 4);
  ush* hib  = hub + NH;
  ush* wkT  = hib + NH;
  int* count  = (int*)(wkT + HID * HID);
  int* start  = count + NTOT;
  int* cursor = start + NTOT;
  int* bsum   = cursor + NTOT;
  int* csr    = bsum + 128;

  float* out_u = (float*)d_out;
  float* out_i = out_u + (size_t)N * OUTD;

  wkt_kernel<<<HID * HID / 256, 256, 0, stream>>>(Wk, wkT);

  proj_kernel<<<N / 16, 256, 0, stream>>>(x_user, Wp_u, bp_u,
                                          ad_iu, as_uu, ad_uu, as_ui, hub, su);
  proj_kernel<<<N / 16, 256, 0, stream>>>(x_item, Wp_i, bp_i,
                                          as_iu, ad_ui, as_ii, ad_ii, hib, si);

  // batched CSR build: rel 0=iu, 1=uu, 2=ui, 3=ii
  hipMemsetAsync(count, 0, NTOT * sizeof(int), stream);
  hist4_kernel<<<4 * EB, 256, 0, stream>>>(e_iu + E, e_uu + E, e_ui + E, e_ii + E, count);
  scanA_kernel<<<SC_NB, SC_TPB, 0, stream>>>(count, bsum);
  scanB_kernel<<<1, 128, 0, stream>>>(bsum);
  scanC_kernel<<<SC_NB, SC_TPB, 0, stream>>>(count, bsum, start, cursor);
  fill4_kernel<<<4 * EB, 256, 0, stream>>>(e_iu, e_iu + E, e_uu, e_uu + E,
                                           e_ui, e_ui + E, e_ii, e_ii + E, cursor, csr);

  const int SEMG = (N + 63) / 64;

  // ---- user side
  conv_kernel<<<N / 4, 256, 0, stream>>>(hib, si, su, csr, start, count, z0);
  conv_kernel<<<N / 4, 256, 0, stream>>>(hub, su + N8, su + 2 * (size_t)N8, csr,
                                         start + N, count + N, z1);
  hipMemsetAsync(sc, 0, 2 * sizeof(float), stream);
  semscore_kernel<<<SEMG, 256, 0, stream>>>(z0, z1, wkT, bk, q, sc);
  attn_kernel<<<1, 1, 0, stream>>>(sc, 1.0f / (float)N);
  final_kernel<<<N / 16, 256, 0, stream>>>(z0, z1, sc + 2, Wl, bl, out_u);

  // ---- item side
  conv_kernel<<<N / 4, 256, 0, stream>>>(hub, su + 3 * (size_t)N8, si + N8, csr,
                                         start + 2 * N, count + 2 * N, z0);
  conv_kernel<<<N / 4, 256, 0, stream>>>(hib, si + 2 * (size_t)N8, si + 3 * (size_t)N8, csr,
                                         start + 3 * N, count + 3 * N, z1);
  hipMemsetAsync(sc, 0, 2 * sizeof(float), stream);
  semscore_kernel<<<SEMG, 256, 0, stream>>>(z0, z1, wkT, bk, q, sc);
  attn_kernel<<<1, 1, 0, stream>>>(sc, 1.0f / (float)N);
  final_kernel<<<N / 16, 256, 0, stream>>>(z0, z1, sc + 2, Wl, bl, out_i);
}